// Round 1
// baseline (319.444 us; speedup 1.0000x reference)
//
#include <hip/hip_runtime.h>
#include <hip/hip_bf16.h>

#define NC   4
#define BB   32
#define NN   2048
#define CI   64
#define CO   64
#define DD   8
#define NPCL 512
#define EW   73   // 1 + 8 + 64 combined basis width

// ---------------------------------------------------------------------------
// Kernel 1: per-client partial aggregates.
// grid = G(4) x B(32) x P(4) = 512 blocks, 256 threads.
// Each block: nodes [n0, n0+128), one batch b, one client g.
// part[g][b][p][e][c] = sum_{n in chunk} te(n,e) * H[b,n,c]
// ---------------------------------------------------------------------------
__global__ __launch_bounds__(256) void k1_partial(
    const float* __restrict__ x, const float* __restrict__ mask,
    const float* __restrict__ E, float* __restrict__ part) {
  __shared__ float H_lds[128][CI];   // 32 KB
  __shared__ float E_lds[128][DD];   // 4 KB
  const int bid = blockIdx.x;        // ((g*32 + b)*4 + p)
  const int g = bid >> 7;
  const int b = (bid >> 2) & 31;
  const int p = bid & 3;
  const int n0 = g * NPCL + p * 128;
  const int tid = threadIdx.x;

  // stage H chunk (vectorized), applying mask
  {
    const float4* xp = reinterpret_cast<const float4*>(x + ((size_t)b * NN + n0) * CI);
    const float4* mp = reinterpret_cast<const float4*>(mask + ((size_t)b * NN + n0) * CI);
    float4* hl = reinterpret_cast<float4*>(&H_lds[0][0]);
    for (int i = tid; i < 128 * CI / 4; i += 256) {
      float4 xv = xp[i], mv = mp[i];
      xv.x *= mv.x; xv.y *= mv.y; xv.z *= mv.z; xv.w *= mv.w;
      hl[i] = xv;
    }
    const float4* ep = reinterpret_cast<const float4*>(E + (size_t)n0 * DD);
    float4* el = reinterpret_cast<float4*>(&E_lds[0][0]);
    if (tid < 128 * DD / 4) el[tid] = ep[tid];
  }
  __syncthreads();

  const int c = tid & 63;
  const int e0 = tid >> 6;  // 0..3 (wave-uniform)
  float acc[19];
#pragma unroll
  for (int j = 0; j < 19; ++j) acc[j] = 0.f;

  for (int n = 0; n < 128; ++n) {
    const float h = H_lds[n][c];
    float ev[8];
    float4 ev0 = *reinterpret_cast<const float4*>(&E_lds[n][0]);
    float4 ev1 = *reinterpret_cast<const float4*>(&E_lds[n][4]);
    ev[0] = ev0.x; ev[1] = ev0.y; ev[2] = ev0.z; ev[3] = ev0.w;
    ev[4] = ev1.x; ev[5] = ev1.y; ev[6] = ev1.z; ev[7] = ev1.w;
#pragma unroll
    for (int j = 0; j < 19; ++j) {
      const int e = e0 + 4 * j;
      if (e < EW) {
        float te;
        if (e == 0) te = 1.f;
        else if (e < 9) te = ev[e - 1];
        else { const int r = e - 9; te = ev[r >> 3] * ev[r & 7]; }
        acc[j] += te * h;
      }
    }
  }

  float* pp = part + (size_t)bid * (EW * CI);
#pragma unroll
  for (int j = 0; j < 19; ++j) {
    const int e = e0 + 4 * j;
    if (e < EW) pp[e * CI + c] = acc[j];
  }
}

// ---------------------------------------------------------------------------
// Kernel 2: reduce partials -> EH, count nonzeros of cl (per-client) and EH.
// 584 blocks x 256 threads = 149504 = 32*73*64 threads, one element each.
// ---------------------------------------------------------------------------
__global__ __launch_bounds__(256) void k2_reduce(
    const float* __restrict__ part, float* __restrict__ EH,
    unsigned int* __restrict__ cnt) {
  const int tid = threadIdx.x;
  const int i = blockIdx.x * 256 + tid;          // (b*73 + e)*64 + c
  const int b = i / (EW * CI);
  const int ec = i - b * (EW * CI);

  float s = 0.f;
  int c1 = 0;
#pragma unroll
  for (int g = 0; g < 4; ++g) {
    float cl = 0.f;
#pragma unroll
    for (int p = 0; p < 4; ++p)
      cl += part[(size_t)(((g * 32 + b) * 4 + p)) * (EW * CI) + ec];
    c1 += (cl != 0.f) ? 1 : 0;
    s += cl;
  }
  const int c2 = (s != 0.f) ? 1 : 0;
  EH[i] = s;

  __shared__ int r1[256], r2[256];
  r1[tid] = c1; r2[tid] = c2;
  __syncthreads();
  for (int st = 128; st > 0; st >>= 1) {
    if (tid < st) { r1[tid] += r1[tid + st]; r2[tid] += r2[tid + st]; }
    __syncthreads();
  }
  if (tid == 0) {
    atomicAdd(&cnt[0], (unsigned int)r1[0]);
    atomicAdd(&cnt[1], (unsigned int)r2[0]);
  }
}

// ---------------------------------------------------------------------------
// Kernel 2b: scalars sp / tran, written to d_out tail.
// ---------------------------------------------------------------------------
__global__ void k2_scalars(const unsigned int* __restrict__ cnt,
                           float* __restrict__ out_scalars) {
  const float num  = (float)cnt[0];
  const float num2 = (float)cnt[1];
  const float den  = (float)(598016.0 + 1e-10);   // 4*32*73*64
  const float den2 = (float)(149504.0 + 1e-10);   // 32*73*64
  const float sp   = 1.0f - num / den;
  const float r2   = num2 / den2;
  const float tran = (1.0f - sp + r2) * 0.5f;
  out_scalars[0] = sp;
  out_scalars[1] = tran;
}

// ---------------------------------------------------------------------------
// Kernel 3: fused Z (poly back-projection + residual) and per-node GEMM.
// 256 blocks x 256 threads, 8 nodes per block.
// ---------------------------------------------------------------------------
__global__ __launch_bounds__(256, 1) void k3_out(
    const float* __restrict__ x, const float* __restrict__ mask,
    const float* __restrict__ E, const float* __restrict__ poly,
    const float* __restrict__ Wp, const float* __restrict__ bp,
    const float* __restrict__ EH, float* __restrict__ out) {
  __shared__ float tep[8][EW];        // te(n,e) * poly[g, k(e)]
  __shared__ float Ee[8][8];
  __shared__ float Z_lds[8][32][66];  // padded stride 66 -> no 8-way conflicts
  __shared__ float W_lds[64][64];

  const int nb = blockIdx.x * 8;
  const int g = nb >> 9;              // 8-node tiles never straddle clients
  const int tid = threadIdx.x;

  if (tid < 64) Ee[tid >> 3][tid & 7] = E[(size_t)(nb + (tid >> 3)) * DD + (tid & 7)];
  __syncthreads();

  const float p0 = poly[g * 3 + 0];
  const float p1 = poly[g * 3 + 1];
  const float p2 = poly[g * 3 + 2];
  for (int idx = tid; idx < 8 * EW; idx += 256) {
    const int nd = idx / EW, e = idx - nd * EW;
    float te, pk;
    if (e == 0) { te = 1.f; pk = p0; }
    else if (e < 9) { te = Ee[nd][e - 1]; pk = p1; }
    else { const int r = e - 9; te = Ee[nd][r >> 3] * Ee[nd][r & 7]; pk = p2; }
    tep[nd][e] = te * pk;
  }
  __syncthreads();

  // ---------------- Phase A: Z = H + sum_e tep[e] * EH[b,e,c] --------------
  const int b = tid >> 3;             // 0..31
  const int c0 = (tid & 7) * 8;       // 8 channels per thread
  float acc[8][8];
#pragma unroll
  for (int nd = 0; nd < 8; ++nd) {
    const float* xp = x + ((size_t)b * NN + nb + nd) * CI + c0;
    const float* mp = mask + ((size_t)b * NN + nb + nd) * CI + c0;
    float4 x0 = *reinterpret_cast<const float4*>(xp);
    float4 x1 = *reinterpret_cast<const float4*>(xp + 4);
    float4 m0 = *reinterpret_cast<const float4*>(mp);
    float4 m1 = *reinterpret_cast<const float4*>(mp + 4);
    acc[nd][0] = x0.x * m0.x; acc[nd][1] = x0.y * m0.y;
    acc[nd][2] = x0.z * m0.z; acc[nd][3] = x0.w * m0.w;
    acc[nd][4] = x1.x * m1.x; acc[nd][5] = x1.y * m1.y;
    acc[nd][6] = x1.z * m1.z; acc[nd][7] = x1.w * m1.w;
  }
  const float* ehb = EH + (size_t)b * (EW * CI) + c0;
  for (int e = 0; e < EW; ++e) {
    float4 h0 = *reinterpret_cast<const float4*>(ehb + e * CI);
    float4 h1 = *reinterpret_cast<const float4*>(ehb + e * CI + 4);
    float eh[8];
    eh[0] = h0.x; eh[1] = h0.y; eh[2] = h0.z; eh[3] = h0.w;
    eh[4] = h1.x; eh[5] = h1.y; eh[6] = h1.z; eh[7] = h1.w;
#pragma unroll
    for (int nd = 0; nd < 8; ++nd) {
      const float t = tep[nd][e];
#pragma unroll
      for (int j = 0; j < 8; ++j) acc[nd][j] += t * eh[j];
    }
  }
#pragma unroll
  for (int nd = 0; nd < 8; ++nd)
#pragma unroll
    for (int j = 0; j < 8; ++j)
      Z_lds[nd][b][c0 + j] = acc[nd][j];
  __syncthreads();

  // ---------------- Phase B: out = Z @ W[n] + bias[n] ----------------------
  const int o0 = (tid & 7) * 8;
  for (int nd = 0; nd < 8; ++nd) {
    // build node-adaptive 64x64 weight in LDS
    for (int idx = tid; idx < 64 * 64; idx += 256) {
      const int i = idx >> 6, o = idx & 63;
      float w = 0.f;
#pragma unroll
      for (int d = 0; d < 8; ++d)
        w += Ee[nd][d] * Wp[((size_t)(g * 8 + d) * 64 + i) * 64 + o];
      W_lds[i][o] = w;
    }
    __syncthreads();

    float ob[8];
#pragma unroll
    for (int j = 0; j < 8; ++j) {
      float bv = 0.f;
#pragma unroll
      for (int d = 0; d < 8; ++d)
        bv += Ee[nd][d] * bp[(size_t)(g * 8 + d) * 64 + o0 + j];
      ob[j] = bv;
    }
    for (int i = 0; i < 64; ++i) {
      const float z = Z_lds[nd][b][i];
      float4 w0 = *reinterpret_cast<const float4*>(&W_lds[i][o0]);
      float4 w1 = *reinterpret_cast<const float4*>(&W_lds[i][o0 + 4]);
      ob[0] += z * w0.x; ob[1] += z * w0.y; ob[2] += z * w0.z; ob[3] += z * w0.w;
      ob[4] += z * w1.x; ob[5] += z * w1.y; ob[6] += z * w1.z; ob[7] += z * w1.w;
    }
    float* op = out + ((size_t)b * NN + nb + nd) * CO + o0;
    float4 s0 = make_float4(ob[0], ob[1], ob[2], ob[3]);
    float4 s1 = make_float4(ob[4], ob[5], ob[6], ob[7]);
    *reinterpret_cast<float4*>(op) = s0;
    *reinterpret_cast<float4*>(op + 4) = s1;
    __syncthreads();   // protect W_lds before next node
  }
}

// ---------------------------------------------------------------------------
extern "C" void kernel_launch(void* const* d_in, const int* in_sizes, int n_in,
                              void* d_out, int out_size, void* d_ws, size_t ws_size,
                              hipStream_t stream) {
  const float* x    = (const float*)d_in[0];
  const float* E    = (const float*)d_in[1];
  const float* poly = (const float*)d_in[2];
  const float* mask = (const float*)d_in[3];
  const float* Wp   = (const float*)d_in[4];
  const float* bp   = (const float*)d_in[5];
  float* out = (float*)d_out;

  char* ws = (char*)d_ws;
  float* part = (float*)ws;                                // 512 * 73*64 floats = 9,568,256 B
  float* EH   = (float*)(ws + 9568256);                    // 149,504 floats = 598,016 B
  unsigned int* cnt = (unsigned int*)(ws + 9568256 + 598016);

  hipMemsetAsync(cnt, 0, 2 * sizeof(unsigned int), stream);
  k1_partial<<<512, 256, 0, stream>>>(x, mask, E, part);
  k2_reduce<<<584, 256, 0, stream>>>(part, EH, cnt);
  k2_scalars<<<1, 1, 0, stream>>>(cnt, out + (size_t)BB * NN * CO);
  k3_out<<<256, 256, 0, stream>>>(x, mask, E, poly, Wp, bp, EH, out);
}

// Round 3
// 91.739 us; speedup vs baseline: 3.4821x; 3.4821x over previous
//
#include <hip/hip_runtime.h>
#include <hip/hip_bf16.h>

#define NC   4
#define BB   32
#define NN   2048
#define CI   64
#define CO   64
#define DD   8
#define NPCL 512
#define EW   73   // 1 + 8 + 64 combined basis width
#define CHN  128  // nodes per k1 chunk

// ---------------------------------------------------------------------------
// k1 body: compile-time e-range [LO, LO+CNT). All te indices constant-folded.
// ---------------------------------------------------------------------------
template<int LO, int CNT>
__device__ __forceinline__ void k1_body(const float (*H_lds)[CI],
                                        const float (*E_lds)[DD],
                                        int c, float* __restrict__ part_out) {
  float acc[CNT];
#pragma unroll
  for (int k = 0; k < CNT; ++k) acc[k] = 0.f;

#pragma unroll 4
  for (int n = 0; n < CHN; ++n) {
    float4 e0 = *reinterpret_cast<const float4*>(&E_lds[n][0]);
    float4 e1 = *reinterpret_cast<const float4*>(&E_lds[n][4]);
    float ev[8];
    ev[0] = e0.x; ev[1] = e0.y; ev[2] = e0.z; ev[3] = e0.w;
    ev[4] = e1.x; ev[5] = e1.y; ev[6] = e1.z; ev[7] = e1.w;
    const float h = H_lds[n][c];
    float evh[8];
#pragma unroll
    for (int d = 0; d < 8; ++d) evh[d] = ev[d] * h;
#pragma unroll
    for (int k = 0; k < CNT; ++k) {
      const int e = LO + k;                 // compile-time after unroll
      if (e == 0) acc[k] += h;
      else if (e < 9) acc[k] += evh[e - 1];
      else {
        const int r = e - 9;
        acc[k] = fmaf(ev[r >> 3], evh[r & 7], acc[k]);
      }
    }
  }
#pragma unroll
  for (int k = 0; k < CNT; ++k) part_out[(LO + k) * CI + c] = acc[k];
}

// ---------------------------------------------------------------------------
// Kernel 1: per-client partial aggregates.
// grid = G(4) x B(32) x P(4) = 512 blocks, 256 threads.
// part[g][b][p][e][c] = sum_{n in chunk} te(n,e) * H[b,n,c]
// ---------------------------------------------------------------------------
__global__ __launch_bounds__(256) void k1_partial(
    const float* __restrict__ x, const float* __restrict__ mask,
    const float* __restrict__ E, float* __restrict__ part) {
  __shared__ float H_lds[CHN][CI];   // 32 KB
  __shared__ float E_lds[CHN][DD];   // 4 KB
  const int bid = blockIdx.x;        // ((g*32 + b)*4 + p)
  const int g = bid >> 7;
  const int b = (bid >> 2) & 31;
  const int p = bid & 3;
  const int n0 = g * NPCL + p * CHN;
  const int tid = threadIdx.x;

  {
    const float4* xp = reinterpret_cast<const float4*>(x + ((size_t)b * NN + n0) * CI);
    const float4* mp = reinterpret_cast<const float4*>(mask + ((size_t)b * NN + n0) * CI);
    float4* hl = reinterpret_cast<float4*>(&H_lds[0][0]);
    for (int i = tid; i < CHN * CI / 4; i += 256) {
      float4 xv = xp[i], mv = mp[i];
      xv.x *= mv.x; xv.y *= mv.y; xv.z *= mv.z; xv.w *= mv.w;
      hl[i] = xv;
    }
    const float4* ep = reinterpret_cast<const float4*>(E + (size_t)n0 * DD);
    float4* el = reinterpret_cast<float4*>(&E_lds[0][0]);
    if (tid < CHN * DD / 4) el[tid] = ep[tid];
  }
  __syncthreads();

  const int c = tid & 63;
  const int q = tid >> 6;            // wave-uniform
  float* pp = part + (size_t)bid * (EW * CI);
  switch (q) {
    case 0: k1_body<0, 19>(H_lds, E_lds, c, pp); break;
    case 1: k1_body<19, 18>(H_lds, E_lds, c, pp); break;
    case 2: k1_body<37, 18>(H_lds, E_lds, c, pp); break;
    default: k1_body<55, 18>(H_lds, E_lds, c, pp); break;
  }
}

// ---------------------------------------------------------------------------
// Kernel 2: reduce partials -> EH, count nonzeros of cl (per-client) and EH.
// ---------------------------------------------------------------------------
__global__ __launch_bounds__(256) void k2_reduce(
    const float* __restrict__ part, float* __restrict__ EH,
    unsigned int* __restrict__ cnt) {
  const int tid = threadIdx.x;
  const int i = blockIdx.x * 256 + tid;          // (b*73 + e)*64 + c
  const int b = i / (EW * CI);
  const int ec = i - b * (EW * CI);

  float s = 0.f;
  int c1 = 0;
#pragma unroll
  for (int g = 0; g < 4; ++g) {
    float cl = 0.f;
#pragma unroll
    for (int p = 0; p < 4; ++p)
      cl += part[(size_t)(((g * 32 + b) * 4 + p)) * (EW * CI) + ec];
    c1 += (cl != 0.f) ? 1 : 0;
    s += cl;
  }
  const int c2 = (s != 0.f) ? 1 : 0;
  EH[i] = s;

  __shared__ int r1[256], r2[256];
  r1[tid] = c1; r2[tid] = c2;
  __syncthreads();
  for (int st = 128; st > 0; st >>= 1) {
    if (tid < st) { r1[tid] += r1[tid + st]; r2[tid] += r2[tid + st]; }
    __syncthreads();
  }
  if (tid == 0) {
    atomicAdd(&cnt[0], (unsigned int)r1[0]);
    atomicAdd(&cnt[1], (unsigned int)r2[0]);
  }
}

// ---------------------------------------------------------------------------
// Kernel 2b: scalars sp / tran.
// ---------------------------------------------------------------------------
__global__ void k2_scalars(const unsigned int* __restrict__ cnt,
                           float* __restrict__ out_scalars) {
  const float num  = (float)cnt[0];
  const float num2 = (float)cnt[1];
  const float den  = (float)(598016.0 + 1e-10);   // 4*32*73*64
  const float den2 = (float)(149504.0 + 1e-10);   // 32*73*64
  const float sp   = 1.0f - num / den;
  const float r2   = num2 / den2;
  const float tran = (1.0f - sp + r2) * 0.5f;
  out_scalars[0] = sp;
  out_scalars[1] = tran;
}

// ---------------------------------------------------------------------------
// Kernel 3: fused Z (poly back-projection + residual) and per-node GEMM.
// 512 blocks x 256 threads, 4 nodes per block. LDS ~52 KB -> 3 blocks/CU.
// ---------------------------------------------------------------------------
__global__ __launch_bounds__(256) void k3_out(
    const float* __restrict__ x, const float* __restrict__ mask,
    const float* __restrict__ E, const float* __restrict__ poly,
    const float* __restrict__ Wp, const float* __restrict__ bp,
    const float* __restrict__ EH, float* __restrict__ out) {
  __shared__ float tep[4][EW];        // te(n,e) * poly[g, k(e)]
  __shared__ float Ee[4][8];
  __shared__ float Z_lds[4][32][66];  // padded stride 66
  __shared__ float W_lds[64][64];

  const int nb = blockIdx.x * 4;
  const int g = nb >> 9;              // 4-node tiles never straddle clients
  const int tid = threadIdx.x;

  if (tid < 32) Ee[tid >> 3][tid & 7] = E[(size_t)(nb + (tid >> 3)) * DD + (tid & 7)];
  __syncthreads();

  const float p0 = poly[g * 3 + 0];
  const float p1 = poly[g * 3 + 1];
  const float p2 = poly[g * 3 + 2];
  for (int idx = tid; idx < 4 * EW; idx += 256) {   // 292 entries > 256 threads!
    const int nd = idx / EW, e = idx - nd * EW;
    float te, pk;
    if (e == 0) { te = 1.f; pk = p0; }
    else if (e < 9) { te = Ee[nd][e - 1]; pk = p1; }
    else { const int r = e - 9; te = Ee[nd][r >> 3] * Ee[nd][r & 7]; pk = p2; }
    tep[nd][e] = te * pk;
  }
  __syncthreads();

  // ---------------- Phase A: Z = H + sum_e tep[e] * EH[b,e,c] --------------
  const int b = tid >> 3;             // 0..31
  const int c0 = (tid & 7) * 8;       // 8 channels per thread
  float acc[4][8];
#pragma unroll
  for (int nd = 0; nd < 4; ++nd) {
    const float* xp = x + ((size_t)b * NN + nb + nd) * CI + c0;
    const float* mp = mask + ((size_t)b * NN + nb + nd) * CI + c0;
    float4 x0 = *reinterpret_cast<const float4*>(xp);
    float4 x1 = *reinterpret_cast<const float4*>(xp + 4);
    float4 m0 = *reinterpret_cast<const float4*>(mp);
    float4 m1 = *reinterpret_cast<const float4*>(mp + 4);
    acc[nd][0] = x0.x * m0.x; acc[nd][1] = x0.y * m0.y;
    acc[nd][2] = x0.z * m0.z; acc[nd][3] = x0.w * m0.w;
    acc[nd][4] = x1.x * m1.x; acc[nd][5] = x1.y * m1.y;
    acc[nd][6] = x1.z * m1.z; acc[nd][7] = x1.w * m1.w;
  }
  const float* ehb = EH + (size_t)b * (EW * CI) + c0;
  for (int e = 0; e < EW; ++e) {
    float4 h0 = *reinterpret_cast<const float4*>(ehb + e * CI);
    float4 h1 = *reinterpret_cast<const float4*>(ehb + e * CI + 4);
    float eh[8];
    eh[0] = h0.x; eh[1] = h0.y; eh[2] = h0.z; eh[3] = h0.w;
    eh[4] = h1.x; eh[5] = h1.y; eh[6] = h1.z; eh[7] = h1.w;
#pragma unroll
    for (int nd = 0; nd < 4; ++nd) {
      const float t = tep[nd][e];
#pragma unroll
      for (int j = 0; j < 8; ++j) acc[nd][j] += t * eh[j];
    }
  }
#pragma unroll
  for (int nd = 0; nd < 4; ++nd)
#pragma unroll
    for (int j = 0; j < 8; ++j)
      Z_lds[nd][b][c0 + j] = acc[nd][j];
  __syncthreads();

  // ---------------- Phase B: out = Z @ W[n] + bias[n] ----------------------
  const int o0 = (tid & 7) * 8;
  for (int nd = 0; nd < 4; ++nd) {
    for (int idx = tid; idx < 64 * 64; idx += 256) {
      const int i = idx >> 6, o = idx & 63;
      float w = 0.f;
#pragma unroll
      for (int d = 0; d < 8; ++d)
        w += Ee[nd][d] * Wp[((size_t)(g * 8 + d) * 64 + i) * 64 + o];
      W_lds[i][o] = w;
    }
    __syncthreads();

    float ob[8];
#pragma unroll
    for (int j = 0; j < 8; ++j) {
      float bv = 0.f;
#pragma unroll
      for (int d = 0; d < 8; ++d)
        bv += Ee[nd][d] * bp[(size_t)(g * 8 + d) * 64 + o0 + j];
      ob[j] = bv;
    }
    for (int i = 0; i < 64; ++i) {
      const float z = Z_lds[nd][b][i];
      float4 w0 = *reinterpret_cast<const float4*>(&W_lds[i][o0]);
      float4 w1 = *reinterpret_cast<const float4*>(&W_lds[i][o0 + 4]);
      ob[0] += z * w0.x; ob[1] += z * w0.y; ob[2] += z * w0.z; ob[3] += z * w0.w;
      ob[4] += z * w1.x; ob[5] += z * w1.y; ob[6] += z * w1.z; ob[7] += z * w1.w;
    }
    float* op = out + ((size_t)b * NN + nb + nd) * CO + o0;
    *reinterpret_cast<float4*>(op) = make_float4(ob[0], ob[1], ob[2], ob[3]);
    *reinterpret_cast<float4*>(op + 4) = make_float4(ob[4], ob[5], ob[6], ob[7]);
    __syncthreads();   // protect W_lds before next node
  }
}

// ---------------------------------------------------------------------------
extern "C" void kernel_launch(void* const* d_in, const int* in_sizes, int n_in,
                              void* d_out, int out_size, void* d_ws, size_t ws_size,
                              hipStream_t stream) {
  const float* x    = (const float*)d_in[0];
  const float* E    = (const float*)d_in[1];
  const float* poly = (const float*)d_in[2];
  const float* mask = (const float*)d_in[3];
  const float* Wp   = (const float*)d_in[4];
  const float* bp   = (const float*)d_in[5];
  float* out = (float*)d_out;

  char* ws = (char*)d_ws;
  float* part = (float*)ws;                                // 512 * 73*64 floats
  float* EH   = (float*)(ws + 9568256);                    // 149,504 floats
  unsigned int* cnt = (unsigned int*)(ws + 9568256 + 598016);

  hipMemsetAsync(cnt, 0, 2 * sizeof(unsigned int), stream);
  k1_partial<<<512, 256, 0, stream>>>(x, mask, E, part);
  k2_reduce<<<584, 256, 0, stream>>>(part, EH, cnt);
  k2_scalars<<<1, 1, 0, stream>>>(cnt, out + (size_t)BB * NN * CO);
  k3_out<<<512, 256, 0, stream>>>(x, mask, E, poly, Wp, bp, EH, out);
}

// Round 4
// 87.689 us; speedup vs baseline: 3.6429x; 1.0462x over previous
//
#include <hip/hip_runtime.h>
#include <hip/hip_bf16.h>

#define NC   4
#define BB   32
#define NN   2048
#define CI   64
#define CO   64
#define DD   8
#define NPCL 512
#define EW   73   // 1 + 8 + 64 combined basis width
#define CHN  128  // nodes per k1 chunk

typedef __attribute__((ext_vector_type(8))) short bf16x8;
typedef __attribute__((ext_vector_type(4))) float f32x4;

__device__ __forceinline__ unsigned int rne_bf16(float f) {
  unsigned int b = __float_as_uint(f);
  return (b + 0x7FFFu + ((b >> 16) & 1u)) >> 16;
}

// ---------------------------------------------------------------------------
// k1 body: compile-time e-range [LO, LO+CNT). All te indices constant-folded.
// ---------------------------------------------------------------------------
template<int LO, int CNT>
__device__ __forceinline__ void k1_body(const float (*H_lds)[CI],
                                        const float (*E_lds)[DD],
                                        int c, float* __restrict__ part_out) {
  float acc[CNT];
#pragma unroll
  for (int k = 0; k < CNT; ++k) acc[k] = 0.f;

#pragma unroll 4
  for (int n = 0; n < CHN; ++n) {
    float4 e0 = *reinterpret_cast<const float4*>(&E_lds[n][0]);
    float4 e1 = *reinterpret_cast<const float4*>(&E_lds[n][4]);
    float ev[8];
    ev[0] = e0.x; ev[1] = e0.y; ev[2] = e0.z; ev[3] = e0.w;
    ev[4] = e1.x; ev[5] = e1.y; ev[6] = e1.z; ev[7] = e1.w;
    const float h = H_lds[n][c];
    float evh[8];
#pragma unroll
    for (int d = 0; d < 8; ++d) evh[d] = ev[d] * h;
#pragma unroll
    for (int k = 0; k < CNT; ++k) {
      const int e = LO + k;                 // compile-time after unroll
      if (e == 0) acc[k] += h;
      else if (e < 9) acc[k] += evh[e - 1];
      else {
        const int r = e - 9;
        acc[k] = fmaf(ev[r >> 3], evh[r & 7], acc[k]);
      }
    }
  }
#pragma unroll
  for (int k = 0; k < CNT; ++k) part_out[(LO + k) * CI + c] = acc[k];
}

// ---------------------------------------------------------------------------
// Kernel 1: per-client partial aggregates (proven round 3, unchanged).
// ---------------------------------------------------------------------------
__global__ __launch_bounds__(256) void k1_partial(
    const float* __restrict__ x, const float* __restrict__ mask,
    const float* __restrict__ E, float* __restrict__ part) {
  __shared__ float H_lds[CHN][CI];   // 32 KB
  __shared__ float E_lds[CHN][DD];   // 4 KB
  const int bid = blockIdx.x;        // ((g*32 + b)*4 + p)
  const int g = bid >> 7;
  const int b = (bid >> 2) & 31;
  const int p = bid & 3;
  const int n0 = g * NPCL + p * CHN;
  const int tid = threadIdx.x;

  {
    const float4* xp = reinterpret_cast<const float4*>(x + ((size_t)b * NN + n0) * CI);
    const float4* mp = reinterpret_cast<const float4*>(mask + ((size_t)b * NN + n0) * CI);
    float4* hl = reinterpret_cast<float4*>(&H_lds[0][0]);
    for (int i = tid; i < CHN * CI / 4; i += 256) {
      float4 xv = xp[i], mv = mp[i];
      xv.x *= mv.x; xv.y *= mv.y; xv.z *= mv.z; xv.w *= mv.w;
      hl[i] = xv;
    }
    const float4* ep = reinterpret_cast<const float4*>(E + (size_t)n0 * DD);
    float4* el = reinterpret_cast<float4*>(&E_lds[0][0]);
    if (tid < CHN * DD / 4) el[tid] = ep[tid];
  }
  __syncthreads();

  const int c = tid & 63;
  const int q = tid >> 6;            // wave-uniform
  float* pp = part + (size_t)bid * (EW * CI);
  switch (q) {
    case 0: k1_body<0, 19>(H_lds, E_lds, c, pp); break;
    case 1: k1_body<19, 18>(H_lds, E_lds, c, pp); break;
    case 2: k1_body<37, 18>(H_lds, E_lds, c, pp); break;
    default: k1_body<55, 18>(H_lds, E_lds, c, pp); break;
  }
}

// ---------------------------------------------------------------------------
// Kernel 2: reduce partials -> EH, count nonzeros (unchanged).
// ---------------------------------------------------------------------------
__global__ __launch_bounds__(256) void k2_reduce(
    const float* __restrict__ part, float* __restrict__ EH,
    unsigned int* __restrict__ cnt) {
  const int tid = threadIdx.x;
  const int i = blockIdx.x * 256 + tid;          // (b*73 + e)*64 + c
  const int b = i / (EW * CI);
  const int ec = i - b * (EW * CI);

  float s = 0.f;
  int c1 = 0;
#pragma unroll
  for (int g = 0; g < 4; ++g) {
    float cl = 0.f;
#pragma unroll
    for (int p = 0; p < 4; ++p)
      cl += part[(size_t)(((g * 32 + b) * 4 + p)) * (EW * CI) + ec];
    c1 += (cl != 0.f) ? 1 : 0;
    s += cl;
  }
  const int c2 = (s != 0.f) ? 1 : 0;
  EH[i] = s;

  __shared__ int r1[256], r2[256];
  r1[tid] = c1; r2[tid] = c2;
  __syncthreads();
  for (int st = 128; st > 0; st >>= 1) {
    if (tid < st) { r1[tid] += r1[tid + st]; r2[tid] += r2[tid + st]; }
    __syncthreads();
  }
  if (tid == 0) {
    atomicAdd(&cnt[0], (unsigned int)r1[0]);
    atomicAdd(&cnt[1], (unsigned int)r2[0]);
  }
}

// ---------------------------------------------------------------------------
// Kernel 2b: scalars sp / tran (unchanged).
// ---------------------------------------------------------------------------
__global__ void k2_scalars(const unsigned int* __restrict__ cnt,
                           float* __restrict__ out_scalars) {
  const float num  = (float)cnt[0];
  const float num2 = (float)cnt[1];
  const float den  = (float)(598016.0 + 1e-10);   // 4*32*73*64
  const float den2 = (float)(149504.0 + 1e-10);   // 32*73*64
  const float sp   = 1.0f - num / den;
  const float r2   = num2 / den2;
  const float tran = (1.0f - sp + r2) * 0.5f;
  out_scalars[0] = sp;
  out_scalars[1] = tran;
}

// ---------------------------------------------------------------------------
// Kernel 0: precompute Wp transposed bf16 [4][64][512] (k = d*64+i) and
// bias vec bvec[n][o] = sum_d E[n,d]*bp[g,d,o] (fp32).
// ---------------------------------------------------------------------------
__global__ __launch_bounds__(256) void k0_pre(
    const float* __restrict__ Wp, const float* __restrict__ bp,
    const float* __restrict__ E,
    unsigned short* __restrict__ Wpt, float* __restrict__ bvec) {
  const int idx = blockIdx.x * 256 + threadIdx.x;
  if (idx < 131072) {
    const int g = idx >> 15, rem = idx & 32767;
    const int o = rem >> 9, k = rem & 511, d = k >> 6, i = k & 63;
    Wpt[idx] = (unsigned short)rne_bf16(Wp[((size_t)(g * 8 + d) * 64 + i) * 64 + o]);
  } else {
    const int j = idx - 131072;      // < 131072
    const int n = j >> 6, o = j & 63, g = n >> 9;
    float s = 0.f;
#pragma unroll
    for (int d = 0; d < 8; ++d)
      s = fmaf(E[(size_t)n * 8 + d], bp[(size_t)(g * 8 + d) * 64 + o], s);
    bvec[j] = s;
  }
}

// ---------------------------------------------------------------------------
// Kernel 3a: Z = H + sum_e tep[n,e]*EH[b,e,c], written as bf16 [b][n][c].
// 1024 blocks (b x 32 node-tiles of 64), 256 threads, ~39KB LDS -> 4/CU.
// ---------------------------------------------------------------------------
__global__ __launch_bounds__(256) void k3a_z(
    const float* __restrict__ x, const float* __restrict__ mask,
    const float* __restrict__ E, const float* __restrict__ poly,
    const float* __restrict__ EH, unsigned short* __restrict__ Zb) {
  __shared__ float EH_s[EW][64];     // 18.7 KB
  __shared__ float tep_s[64][EW];    // 18.7 KB
  __shared__ float E_s[64][8];       // 2 KB

  const int blk = blockIdx.x;        // b*32 + nt
  const int b  = blk >> 5;
  const int n0 = (blk & 31) << 6;
  const int g  = n0 >> 9;
  const int tid = threadIdx.x;

  if (tid < 128) {
    const int row = tid >> 1, h = tid & 1;
    *(float4*)&E_s[row][h * 4] = *(const float4*)&E[(size_t)(n0 + row) * 8 + h * 4];
  }
  {
    const float4* src = (const float4*)(EH + (size_t)b * (EW * 64));
    float4* dst = (float4*)&EH_s[0][0];
    for (int i = tid; i < EW * 16; i += 256) dst[i] = src[i];
  }
  __syncthreads();

  const float p0 = poly[g * 3 + 0], p1 = poly[g * 3 + 1], p2 = poly[g * 3 + 2];
  for (int idx = tid; idx < 64 * EW; idx += 256) {
    const int nd = idx & 63, e = idx >> 6;   // e in 0..72
    float te, pk;
    if (e == 0) { te = 1.f; pk = p0; }
    else if (e < 9) { te = E_s[nd][e - 1]; pk = p1; }
    else { const int r = e - 9; te = E_s[nd][r >> 3] * E_s[nd][r & 7]; pk = p2; }
    tep_s[nd][e] = te * pk;
  }
  __syncthreads();

  const int c0 = (tid & 7) * 8;
  const int ndl = tid >> 3;          // 0..31
  float acc[2][8];
#pragma unroll
  for (int u = 0; u < 2; ++u) {
    const int n = n0 + ndl + u * 32;
    const float4* xp = (const float4*)(x + ((size_t)b * NN + n) * CI + c0);
    const float4* mp = (const float4*)(mask + ((size_t)b * NN + n) * CI + c0);
    float4 x0 = xp[0], x1 = xp[1], m0 = mp[0], m1 = mp[1];
    acc[u][0] = x0.x * m0.x; acc[u][1] = x0.y * m0.y;
    acc[u][2] = x0.z * m0.z; acc[u][3] = x0.w * m0.w;
    acc[u][4] = x1.x * m1.x; acc[u][5] = x1.y * m1.y;
    acc[u][6] = x1.z * m1.z; acc[u][7] = x1.w * m1.w;
  }
#pragma unroll 1
  for (int e = 0; e < EW; ++e) {
    float4 h0 = *(const float4*)&EH_s[e][c0];
    float4 h1 = *(const float4*)&EH_s[e][c0 + 4];
    const float t0 = tep_s[ndl][e];
    const float t1 = tep_s[ndl + 32][e];
    acc[0][0] = fmaf(t0, h0.x, acc[0][0]); acc[0][1] = fmaf(t0, h0.y, acc[0][1]);
    acc[0][2] = fmaf(t0, h0.z, acc[0][2]); acc[0][3] = fmaf(t0, h0.w, acc[0][3]);
    acc[0][4] = fmaf(t0, h1.x, acc[0][4]); acc[0][5] = fmaf(t0, h1.y, acc[0][5]);
    acc[0][6] = fmaf(t0, h1.z, acc[0][6]); acc[0][7] = fmaf(t0, h1.w, acc[0][7]);
    acc[1][0] = fmaf(t1, h0.x, acc[1][0]); acc[1][1] = fmaf(t1, h0.y, acc[1][1]);
    acc[1][2] = fmaf(t1, h0.z, acc[1][2]); acc[1][3] = fmaf(t1, h0.w, acc[1][3]);
    acc[1][4] = fmaf(t1, h1.x, acc[1][4]); acc[1][5] = fmaf(t1, h1.y, acc[1][5]);
    acc[1][6] = fmaf(t1, h1.z, acc[1][6]); acc[1][7] = fmaf(t1, h1.w, acc[1][7]);
  }
#pragma unroll
  for (int u = 0; u < 2; ++u) {
    unsigned int w[4];
#pragma unroll
    for (int q = 0; q < 4; ++q) {
      unsigned int lo = rne_bf16(acc[u][2 * q]);
      unsigned int hb = __float_as_uint(acc[u][2 * q + 1]);
      unsigned int hi = (hb + 0x7FFFu + ((hb >> 16) & 1u)) & 0xFFFF0000u;
      w[q] = hi | lo;
    }
    const int n = n0 + ndl + u * 32;
    *(uint4*)(Zb + ((size_t)b * NN + n) * CI + c0) = *(uint4*)w;
  }
}

// ---------------------------------------------------------------------------
// Kernel 3b: out[b,n,:] = sum_d E[n,d]*(Z[b,n,:] @ Wp[g,d]) + bvec[n,:]
// via MFMA 16x16x32 bf16. 512 blocks (b x 16 tiles of 128 rows), 4 waves.
// Per wave: 32 rows (2 frags) x 64 cols (4 frags). K=64 per d, 8 d's;
// per-d partial combined with E[row][d] in registers (avoids A-scaling).
// ---------------------------------------------------------------------------
__global__ __launch_bounds__(256) void k3b_gemm(
    const unsigned short* __restrict__ Zb,
    const unsigned short* __restrict__ Wpt,
    const float* __restrict__ E,
    const float* __restrict__ bvec,
    float* __restrict__ out) {
  __shared__ unsigned short Z_lds[128][72];      // 18.4 KB (pad -> 16B-aligned rows)
  __shared__ unsigned short Bt[2][64][40];       // 10.2 KB dbuf, [o][k-slice 32]
  __shared__ float E_lds[128][8];                // 4 KB

  const int blk = blockIdx.x;
  const int b  = blk >> 4;
  const int n0 = (blk & 15) << 7;
  const int g  = n0 >> 9;
  const int tid = threadIdx.x;
  const int wave = tid >> 6;
  const int lane = tid & 63;
  const int l15 = lane & 15;
  const int kg  = lane >> 4;         // 0..3
  const int wrow = wave * 32;

  // stage Z tile: 128 rows x 64 bf16
  {
    const int row = tid >> 1, half = tid & 1;
    const bf16x8* src = (const bf16x8*)(Zb + ((size_t)b * NN + n0 + row) * CI + half * 32);
    bf16x8* dst = (bf16x8*)&Z_lds[row][half * 32];
#pragma unroll
    for (int q = 0; q < 4; ++q) dst[q] = src[q];
  }
  // stage E tile
  {
    const int row = tid >> 1, h = tid & 1;
    *(float4*)&E_lds[row][h * 4] = *(const float4*)&E[(size_t)(n0 + row) * 8 + h * 4];
  }
  // stage B slice 0
  const int so = tid >> 2, skq = tid & 3;
  *(bf16x8*)&Bt[0][so][skq * 8] =
      *(const bf16x8*)(Wpt + ((size_t)g * 64 + so) * 512 + skq * 8);
  __syncthreads();

  f32x4 fin[2][4];
#pragma unroll
  for (int i = 0; i < 2; ++i)
#pragma unroll
    for (int j = 0; j < 4; ++j) fin[i][j] = (f32x4){0.f, 0.f, 0.f, 0.f};
  const f32x4 zf = (f32x4){0.f, 0.f, 0.f, 0.f};

  for (int d = 0; d < 8; ++d) {
    f32x4 tmp[2][4];
#pragma unroll
    for (int st = 0; st < 2; ++st) {
      const int s = d * 2 + st;
      // T14: issue next B-slice load early, ds_write after compute
      bf16x8 nxt;
      if (s < 15)
        nxt = *(const bf16x8*)(Wpt + ((size_t)g * 64 + so) * 512 + (s + 1) * 32 + skq * 8);
      const int buf = s & 1;
      // A frags (rows l15, k contiguous 8 at (l>>4)*8) — no scaling
      bf16x8 a0 = *(const bf16x8*)&Z_lds[wrow + l15][st * 32 + kg * 8];
      bf16x8 a1 = *(const bf16x8*)&Z_lds[wrow + 16 + l15][st * 32 + kg * 8];
      // B frags (cols cf*16+l15)
      bf16x8 b0 = *(const bf16x8*)&Bt[buf][l15][kg * 8];
      bf16x8 b1 = *(const bf16x8*)&Bt[buf][l15 + 16][kg * 8];
      bf16x8 b2 = *(const bf16x8*)&Bt[buf][l15 + 32][kg * 8];
      bf16x8 b3 = *(const bf16x8*)&Bt[buf][l15 + 48][kg * 8];
      if (st == 0) {
        tmp[0][0] = __builtin_amdgcn_mfma_f32_16x16x32_bf16(a0, b0, zf, 0, 0, 0);
        tmp[0][1] = __builtin_amdgcn_mfma_f32_16x16x32_bf16(a0, b1, zf, 0, 0, 0);
        tmp[0][2] = __builtin_amdgcn_mfma_f32_16x16x32_bf16(a0, b2, zf, 0, 0, 0);
        tmp[0][3] = __builtin_amdgcn_mfma_f32_16x16x32_bf16(a0, b3, zf, 0, 0, 0);
        tmp[1][0] = __builtin_amdgcn_mfma_f32_16x16x32_bf16(a1, b0, zf, 0, 0, 0);
        tmp[1][1] = __builtin_amdgcn_mfma_f32_16x16x32_bf16(a1, b1, zf, 0, 0, 0);
        tmp[1][2] = __builtin_amdgcn_mfma_f32_16x16x32_bf16(a1, b2, zf, 0, 0, 0);
        tmp[1][3] = __builtin_amdgcn_mfma_f32_16x16x32_bf16(a1, b3, zf, 0, 0, 0);
      } else {
        tmp[0][0] = __builtin_amdgcn_mfma_f32_16x16x32_bf16(a0, b0, tmp[0][0], 0, 0, 0);
        tmp[0][1] = __builtin_amdgcn_mfma_f32_16x16x32_bf16(a0, b1, tmp[0][1], 0, 0, 0);
        tmp[0][2] = __builtin_amdgcn_mfma_f32_16x16x32_bf16(a0, b2, tmp[0][2], 0, 0, 0);
        tmp[0][3] = __builtin_amdgcn_mfma_f32_16x16x32_bf16(a0, b3, tmp[0][3], 0, 0, 0);
        tmp[1][0] = __builtin_amdgcn_mfma_f32_16x16x32_bf16(a1, b0, tmp[1][0], 0, 0, 0);
        tmp[1][1] = __builtin_amdgcn_mfma_f32_16x16x32_bf16(a1, b1, tmp[1][1], 0, 0, 0);
        tmp[1][2] = __builtin_amdgcn_mfma_f32_16x16x32_bf16(a1, b2, tmp[1][2], 0, 0, 0);
        tmp[1][3] = __builtin_amdgcn_mfma_f32_16x16x32_bf16(a1, b3, tmp[1][3], 0, 0, 0);
      }
      if (s < 15) *(bf16x8*)&Bt[buf ^ 1][so][skq * 8] = nxt;
      __syncthreads();
    }
    // combine: fin += E[row][d] * tmp   (C rows = kg*4+j)
#pragma unroll
    for (int rf = 0; rf < 2; ++rf)
#pragma unroll
      for (int j = 0; j < 4; ++j) {
        const float ev = E_lds[wrow + rf * 16 + kg * 4 + j][d];
#pragma unroll
        for (int cf = 0; cf < 4; ++cf)
          fin[rf][cf][j] = fmaf(ev, tmp[rf][cf][j], fin[rf][cf][j]);
      }
  }

  // epilogue: + bvec, write out
#pragma unroll
  for (int rf = 0; rf < 2; ++rf)
#pragma unroll
    for (int j = 0; j < 4; ++j) {
      const int n = n0 + wrow + rf * 16 + kg * 4 + j;
      const float* bv = bvec + (size_t)n * 64 + l15;
      float* op = out + ((size_t)b * NN + n) * CO + l15;
#pragma unroll
      for (int cf = 0; cf < 4; ++cf)
        op[cf * 16] = fin[rf][cf][j] + bv[cf * 16];
    }
}

// ---------------------------------------------------------------------------
// ws layout (total 10,166,280 B — identical footprint to proven rounds):
//   [0,        9,568,256): part (k1->k2), then reused from k3a on:
//       [0,       8,388,608): Zb bf16 [32][2048][64]
//       [8,388,608, 8,650,752): Wpt bf16 [4][64][512]
//       [8,650,752, 9,175,040): bvec f32 [2048][64]
//   [9,568,256, 10,166,272): EH f32
//   [10,166,272, +8): cnt
// ---------------------------------------------------------------------------
extern "C" void kernel_launch(void* const* d_in, const int* in_sizes, int n_in,
                              void* d_out, int out_size, void* d_ws, size_t ws_size,
                              hipStream_t stream) {
  const float* x    = (const float*)d_in[0];
  const float* E    = (const float*)d_in[1];
  const float* poly = (const float*)d_in[2];
  const float* mask = (const float*)d_in[3];
  const float* Wp   = (const float*)d_in[4];
  const float* bp   = (const float*)d_in[5];
  float* out = (float*)d_out;

  char* ws = (char*)d_ws;
  float* part          = (float*)ws;
  unsigned short* Zb   = (unsigned short*)ws;
  unsigned short* Wpt  = (unsigned short*)(ws + 8388608);
  float* bvec          = (float*)(ws + 8650752);
  float* EH            = (float*)(ws + 9568256);
  unsigned int* cnt    = (unsigned int*)(ws + 10166272);

  hipMemsetAsync(cnt, 0, 2 * sizeof(unsigned int), stream);
  k1_partial<<<512, 256, 0, stream>>>(x, mask, E, part);
  k2_reduce<<<584, 256, 0, stream>>>(part, EH, cnt);
  k2_scalars<<<1, 1, 0, stream>>>(cnt, out + (size_t)BB * NN * CO);
  k0_pre<<<1024, 256, 0, stream>>>(Wp, bp, E, Wpt, bvec);   // after k2: overwrites part tail
  k3a_z<<<1024, 256, 0, stream>>>(x, mask, E, poly, EH, Zb); // overwrites part head
  k3b_gemm<<<512, 256, 0, stream>>>(Zb, Wpt, E, bvec, out);
}